// Round 13
// baseline (348.491 us; speedup 1.0000x reference)
//
#include <hip/hip_runtime.h>
#include <hip/hip_bf16.h>
#include <hip/hip_cooperative_groups.h>

#define RTOT 49152
#define RT9  442368               // (RTOT/8)*72, V-interleaved per-head stride
#define EPSF 1e-5f
#define SCQ 0.5101062398836783f   // (1/sqrt(8)) * log2(e)
#define NBLK 192

typedef _Float16 h2 __attribute__((ext_vector_type(2)));
typedef _Float16 half8 __attribute__((ext_vector_type(8)));
typedef float f32x16 __attribute__((ext_vector_type(16)));

__device__ __forceinline__ h2 cvt2h(float a, float b) {
    return __builtin_bit_cast(h2, __builtin_amdgcn_cvt_pkrtz(a, b));
}
__device__ __forceinline__ unsigned int bcu(h2 v) { return __builtin_bit_cast(unsigned int, v); }

__device__ __forceinline__ void swap32(unsigned int& x, unsigned int& y, int hi) {
#if __has_builtin(__builtin_amdgcn_permlane32_swap)
    auto r = __builtin_amdgcn_permlane32_swap(x, y, false, false);
    x = r[0]; y = r[1];
#else
    unsigned int xs = (unsigned int)__shfl_xor((int)x, 32, 64);
    unsigned int ys = (unsigned int)__shfl_xor((int)y, 32, 64);
    unsigned int nx = hi ? ys : x;
    unsigned int ny = hi ? y : xs;
    x = nx; y = ny;
#endif
}

__device__ __forceinline__ half8 ldaf(const float* __restrict__ X, size_t base) {
    const float4* p = (const float4*)(X + base);
    float4 x = p[0], y = p[1];
    uint4 u = make_uint4(bcu(cvt2h(x.x, x.y)), bcu(cvt2h(x.z, x.w)),
                         bcu(cvt2h(y.x, y.y)), bcu(cvt2h(y.z, y.w)));
    return __builtin_bit_cast(half8, u);
}
__device__ __forceinline__ half8 ldbf(const char* WT, int e, int k0) {
    int off = ((e * 64 + k0) * 2) ^ ((e & 7) << 4);
    return *(const half8*)(WT + off);
}

struct P1S { char WT[3][8192]; float red[384]; };
struct P2S { _Float16 YT[256 * 72]; };
struct P3S { _Float16 KL[4096]; _Float16 VS[4608]; _Float16 OL[4096]; };
struct P4S { char WTo[8192]; float red2[128]; };
union __align__(16) SMem { P1S p1; P2S p2; P3S p3; P4S p4; };

// ===========================================================================
// MEGA: entire MAB in one cooperative kernel, 192 blocks x 512 threads.
// P1 QKV-GEMM -> sp1 partials | sync | P2 reduce+transform -> Qt/Kt/Vr |
// sync | P3 attention x4 -> Ob | sync | P4 O-GEMM -> sp2 | sync | P5 out.
// Fragment layout (verified R4-R12): A/B lane&31 = M/N idx, lane>>5 = k-half;
// D row=(r&3)+8(r>>2)+4hi, col=lane&31.
// ===========================================================================
__global__ __launch_bounds__(512) void mab_mega(
        const float* __restrict__ Qin, const float* __restrict__ Kin,
        const float* __restrict__ mask,
        const float* __restrict__ Wq, const float* __restrict__ bq,
        const float* __restrict__ gq, const float* __restrict__ beq,
        const float* __restrict__ Wk, const float* __restrict__ bk,
        const float* __restrict__ gk, const float* __restrict__ bek,
        const float* __restrict__ Wv, const float* __restrict__ bv,
        const float* __restrict__ gv, const float* __restrict__ bev,
        const float* __restrict__ Wo, const float* __restrict__ bo,
        const float* __restrict__ go, const float* __restrict__ beo,
        _Float16* __restrict__ Qt, _Float16* __restrict__ Kt,
        _Float16* __restrict__ Vr, _Float16* __restrict__ Ob,
        float* __restrict__ sp1, float* __restrict__ sp2,
        float* __restrict__ out) {
    __shared__ SMem U;
    __shared__ _Float16 zl[2048];   // [h][256] mask factors, lives P1->P2
    __shared__ float CF[384];

    int tid = threadIdx.x;
    int wv = tid >> 6, lane = tid & 63, ln = lane & 31, hi = lane >> 5;
    int rbase = blockIdx.x * 256;

    // ---------------- P1: QKV GEMM ----------------
#pragma unroll
    for (int j = 0; j < 8; j++) {
        int i = j * 512 + tid; int d = i >> 6, e = i & 63;
        int off = ((e * 64 + d) * 2) ^ ((e & 7) << 4);
        *(_Float16*)(&U.p1.WT[0][off]) = (_Float16)Wq[i];
    }
#pragma unroll
    for (int j = 0; j < 8; j++) {
        int i = j * 512 + tid; int d = i >> 6, e = i & 63;
        int off = ((e * 64 + d) * 2) ^ ((e & 7) << 4);
        *(_Float16*)(&U.p1.WT[1][off]) = (_Float16)Wk[i];
    }
#pragma unroll
    for (int j = 0; j < 8; j++) {
        int i = j * 512 + tid; int d = i >> 6, e = i & 63;
        int off = ((e * 64 + d) * 2) ^ ((e & 7) << 4);
        *(_Float16*)(&U.p1.WT[2][off]) = (_Float16)Wv[i];
    }
    if (tid < 384) U.p1.red[tid] = 0.f;

    // mask row-sums -> zl
    if (tid < 256) {
        int row = rbase + tid;
        const float4* mr = (const float4*)(mask + (size_t)row * 64);
        float s[8];
#pragma unroll
        for (int h8 = 0; h8 < 8; h8++) s[h8] = 0.f;
#pragma unroll
        for (int i = 0; i < 16; i++) {
            float4 m = mr[i];
            s[i >> 1] += m.x + m.y + m.z + m.w;
        }
#pragma unroll
        for (int h8 = 0; h8 < 8; h8++)
            zl[h8 * 256 + tid] = (_Float16)((s[h8] == 0.f) ? 0.f : SCQ);
    }

    int rowA = rbase + wv * 32 + ln;
    half8 afq[4], afk[4];
#pragma unroll
    for (int kc = 0; kc < 4; kc++) {
        afq[kc] = ldaf(Qin, (size_t)rowA * 64 + kc * 16 + 8 * hi);
        afk[kc] = ldaf(Kin, (size_t)rowA * 64 + kc * 16 + 8 * hi);
    }
    __syncthreads();

    f32x16 accq[2], acck[2], accv[2];
#pragma unroll
    for (int ct = 0; ct < 2; ct++) {
#pragma unroll
        for (int r = 0; r < 16; r++) { accq[ct][r] = 0.f; acck[ct][r] = 0.f; accv[ct][r] = 0.f; }
    }
#pragma unroll
    for (int ct = 0; ct < 2; ct++) {
        int e = ct * 32 + ln;
#pragma unroll
        for (int kc = 0; kc < 4; kc++) {
            half8 bfq = ldbf(U.p1.WT[0], e, kc * 16 + 8 * hi);
            accq[ct] = __builtin_amdgcn_mfma_f32_32x32x16_f16(afq[kc], bfq, accq[ct], 0, 0, 0);
            half8 bfk = ldbf(U.p1.WT[1], e, kc * 16 + 8 * hi);
            acck[ct] = __builtin_amdgcn_mfma_f32_32x32x16_f16(afk[kc], bfk, acck[ct], 0, 0, 0);
            half8 bfv = ldbf(U.p1.WT[2], e, kc * 16 + 8 * hi);
            accv[ct] = __builtin_amdgcn_mfma_f32_32x32x16_f16(afk[kc], bfv, accv[ct], 0, 0, 0);
        }
    }
    // bias + stats partials (LDS)
#pragma unroll
    for (int ct = 0; ct < 2; ct++) {
        int cc = ct * 32 + ln;
        float b0 = bq[cc], s = 0.f, q = 0.f;
#pragma unroll
        for (int r = 0; r < 16; r++) { float v = accq[ct][r] + b0; accq[ct][r] = v; s += v; q += v * v; }
        s += __shfl_xor(s, 32, 64); q += __shfl_xor(q, 32, 64);
        if (lane < 32) { atomicAdd(&U.p1.red[cc], s); atomicAdd(&U.p1.red[64 + cc], q); }
        b0 = bk[cc]; s = 0.f; q = 0.f;
#pragma unroll
        for (int r = 0; r < 16; r++) { float v = acck[ct][r] + b0; acck[ct][r] = v; s += v; q += v * v; }
        s += __shfl_xor(s, 32, 64); q += __shfl_xor(q, 32, 64);
        if (lane < 32) { atomicAdd(&U.p1.red[128 + cc], s); atomicAdd(&U.p1.red[128 + 64 + cc], q); }
        b0 = bv[cc]; s = 0.f; q = 0.f;
#pragma unroll
        for (int r = 0; r < 16; r++) { float v = accv[ct][r] + b0; accv[ct][r] = v; s += v; q += v * v; }
        s += __shfl_xor(s, 32, 64); q += __shfl_xor(q, 32, 64);
        if (lane < 32) { atomicAdd(&U.p1.red[256 + cc], s); atomicAdd(&U.p1.red[256 + 64 + cc], q); }
    }
    __syncthreads();
    if (tid < 384) sp1[blockIdx.x * 384 + tid] = U.p1.red[tid];
    __threadfence();
    cooperative_groups::this_grid().sync();

    // ---------------- P2: reduce stats, transform, write Qt/Kt/Vr ----------
    if (tid < 192) {
        int o = tid >> 6, c = tid & 63;
        float s = 0.f, q = 0.f;
        for (int b = 0; b < NBLK; b++) {
            const float* pp = sp1 + b * 384 + o * 128;
            s += pp[c]; q += pp[64 + c];
        }
        float inv = 1.f / (float)RTOT;
        float mean = s * inv;
        float var  = q * inv - mean * mean;
        const float* g  = o == 0 ? gq : (o == 1 ? gk : gv);
        const float* be = o == 0 ? beq : (o == 1 ? bek : bev);
        float a = g[c] * rsqrtf(var + EPSF);
        CF[o * 128 + c] = a;
        CF[o * 128 + 64 + c] = be[c] - mean * a;
    }
    __syncthreads();

    // Q: transform (+mask zm) -> YT -> coalesced head-major store
#pragma unroll
    for (int ct = 0; ct < 2; ct++) {
        int cc = ct * 32 + ln;
        float a = CF[cc], b = CF[64 + cc];
#pragma unroll
        for (int r = 0; r < 16; r++) {
            int lrow = wv * 32 + (r & 3) + 8 * (r >> 2) + 4 * hi;
            float t = fmaxf(a * accq[ct][r] + b, 0.f) * (float)zl[(cc >> 3) * 256 + lrow];
            U.p2.YT[lrow * 72 + cc] = (_Float16)t;
        }
    }
    __syncthreads();
#pragma unroll
    for (int j = 0; j < 4; j++) {
        int idx = j * 512 + tid, r = idx & 255, h = idx >> 8;
        *(half8*)(Qt + ((size_t)h * RTOT + rbase + r) * 8) = *(const half8*)&U.p2.YT[r * 72 + h * 8];
    }
    __syncthreads();
    // K
#pragma unroll
    for (int ct = 0; ct < 2; ct++) {
        int cc = ct * 32 + ln;
        float a = CF[128 + cc], b = CF[128 + 64 + cc];
#pragma unroll
        for (int r = 0; r < 16; r++) {
            int lrow = wv * 32 + (r & 3) + 8 * (r >> 2) + 4 * hi;
            U.p2.YT[lrow * 72 + cc] = (_Float16)fmaxf(a * acck[ct][r] + b, 0.f);
        }
    }
    __syncthreads();
#pragma unroll
    for (int j = 0; j < 4; j++) {
        int idx = j * 512 + tid, r = idx & 255, h = idx >> 8;
        *(half8*)(Kt + ((size_t)h * RTOT + rbase + r) * 8) = *(const half8*)&U.p2.YT[r * 72 + h * 8];
    }
    __syncthreads();
    // V -> interleaved [h][chunk][9][8] + ones
#pragma unroll
    for (int ct = 0; ct < 2; ct++) {
        int cc = ct * 32 + ln;
        float a = CF[256 + cc], b = CF[256 + 64 + cc];
#pragma unroll
        for (int r = 0; r < 16; r++) {
            int lrow = wv * 32 + (r & 3) + 8 * (r >> 2) + 4 * hi;
            U.p2.YT[lrow * 72 + cc] = (_Float16)fmaxf(a * accv[ct][r] + b, 0.f);
        }
    }
    __syncthreads();
    {
        int chBase = blockIdx.x * 32;
#pragma unroll
        for (int j = 0; j < 4; j++) {
            int idx = j * 512 + tid;
            int h = idx >> 8, rem = idx & 255, ch = rem >> 3, c = rem & 7;
            half8 w;
#pragma unroll
            for (int i = 0; i < 8; i++)
                w[i] = U.p2.YT[(ch * 8 + i) * 72 + h * 8 + c];
            *(half8*)(Vr + (size_t)h * RT9 + (size_t)(chBase + ch) * 72 + c * 8) = w;
        }
        if (tid < 256) {
            int h = tid >> 5, ch = tid & 31;
            half8 one8;
#pragma unroll
            for (int i = 0; i < 8; i++) one8[i] = (_Float16)1.0f;
            *(half8*)(Vr + (size_t)h * RT9 + (size_t)(chBase + ch) * 72 + 64) = one8;
        }
    }
    __threadfence();
    cooperative_groups::this_grid().sync();

    // ---------------- P3: attention, 4 problems/block ----------------
    {
        f32x16 zacc, m12;
#pragma unroll
        for (int r = 0; r < 16; r++) { zacc[r] = 0.f; m12[r] = -12.f; }
        half8 hzero;
#pragma unroll
        for (int i = 0; i < 8; i++) hzero[i] = (_Float16)0.f;

        for (int pr = 0; pr < 4; pr++) {
            int p = blockIdx.x * 4 + pr;
            int h = p / 96, bt = p - h * 96;
            int row0 = bt * 512;
            const _Float16* Kth = Kt + ((size_t)h * RTOT + row0) * 8;
            const _Float16* Vrh = Vr + (size_t)h * RT9 + (size_t)(row0 >> 3) * 72;
            const _Float16* Qth = Qt + ((size_t)h * RTOT + row0) * 8;

            ((uint4*)U.p3.KL)[tid] = ((const uint4*)Kth)[tid];
            ((uint4*)U.p3.VS)[tid] = ((const uint4*)Vrh)[tid];
            if (tid < 64) ((uint4*)U.p3.VS)[512 + tid] = ((const uint4*)Vrh)[512 + tid];
            __syncthreads();

#pragma unroll
            for (int ss = 0; ss < 2; ss++) {
                int n0 = (wv + 8 * ss) * 32;
                half8 qf = hzero;
                if (!hi) qf = *(const half8*)(Qth + (n0 + ln) * 8);
                f32x16 acc = zacc;
#pragma unroll 4
                for (int t = 0; t < 16; t++) {
                    half8 kf = hzero;
                    if (!hi) kf = *(const half8*)&U.p3.KL[(t * 32 + ln) * 8];
                    f32x16 sv = __builtin_amdgcn_mfma_f32_32x32x16_f16(kf, qf, m12, 0, 0, 0);
                    float pe[16];
#pragma unroll
                    for (int r = 0; r < 16; r++)
                        pe[r] = __builtin_amdgcn_exp2f(sv[r]);
#pragma unroll
                    for (int ks = 0; ks < 2; ks++) {
                        unsigned int x1 = bcu(cvt2h(pe[8*ks+0], pe[8*ks+1]));
                        unsigned int x2 = bcu(cvt2h(pe[8*ks+2], pe[8*ks+3]));
                        unsigned int y1 = bcu(cvt2h(pe[8*ks+4], pe[8*ks+5]));
                        unsigned int y2 = bcu(cvt2h(pe[8*ks+6], pe[8*ks+7]));
                        swap32(x1, y1, hi);
                        swap32(x2, y2, hi);
                        uint4 pw = make_uint4(x1, x2, y1, y2);
                        half8 pa = __builtin_bit_cast(half8, pw);
                        int chunk = t * 4 + ks * 2 + hi;
                        half8 vf = hzero;
                        if (ln <= 8) vf = *(const half8*)&U.p3.VS[chunk * 72 + ln * 8];
                        acc = __builtin_amdgcn_mfma_f32_32x32x16_f16(pa, vf, acc, 0, 0, 0);
                    }
                }
#pragma unroll
                for (int r = 0; r < 16; r++) {
                    float av = acc[r];
                    float den = __shfl(av, 8 + 32 * hi, 64);
                    float ov = av * __builtin_amdgcn_rcpf(den);
                    if (ln < 8) {
                        int nrow = n0 + (r & 3) + 8 * (r >> 2) + 4 * hi;
                        U.p3.OL[nrow * 8 + ln] = (_Float16)ov;
                    }
                }
            }
            __syncthreads();
            ((uint4*)(Ob + ((size_t)h * RTOT + row0) * 8))[tid] = ((const uint4*)U.p3.OL)[tid];
        }
    }
    __threadfence();
    cooperative_groups::this_grid().sync();

    // ---------------- P4: O-projection GEMM ----------------
#pragma unroll
    for (int j = 0; j < 8; j++) {
        int i = j * 512 + tid; int d = i >> 6, e = i & 63;
        int off = ((e * 64 + d) * 2) ^ ((e & 7) << 4);
        *(_Float16*)(&U.p4.WTo[off]) = (_Float16)Wo[i];
    }
    if (tid < 128) U.p4.red2[tid] = 0.f;
    half8 afo[4];
#pragma unroll
    for (int kc = 0; kc < 4; kc++)
        afo[kc] = *(const half8*)(Ob + ((size_t)(2*kc + hi) * RTOT + rbase + wv*32 + ln) * 8);
    __syncthreads();

    f32x16 acco[2];
#pragma unroll
    for (int ct = 0; ct < 2; ct++) {
#pragma unroll
        for (int r = 0; r < 16; r++) acco[ct][r] = 0.f;
        int e = ct * 32 + ln;
#pragma unroll
        for (int kc = 0; kc < 4; kc++) {
            half8 bf = ldbf(U.p4.WTo, e, kc * 16 + 8 * hi);
            acco[ct] = __builtin_amdgcn_mfma_f32_32x32x16_f16(afo[kc], bf, acco[ct], 0, 0, 0);
        }
    }
#pragma unroll
    for (int ct = 0; ct < 2; ct++) {
        int cc = ct * 32 + ln;
        float b0 = bo[cc], s = 0.f, q = 0.f;
#pragma unroll
        for (int r = 0; r < 16; r++) { float v = acco[ct][r] + b0; acco[ct][r] = v; s += v; q += v * v; }
        s += __shfl_xor(s, 32, 64); q += __shfl_xor(q, 32, 64);
        if (lane < 32) { atomicAdd(&U.p4.red2[cc], s); atomicAdd(&U.p4.red2[64 + cc], q); }
    }
    __syncthreads();
    if (tid < 128) sp2[blockIdx.x * 128 + tid] = U.p4.red2[tid];
    __threadfence();
    cooperative_groups::this_grid().sync();

    // ---------------- P5: finalize + BN-ReLU -> out ----------------
    if (tid < 64) {
        float s = 0.f, q = 0.f;
        for (int b = 0; b < NBLK; b++) {
            const float* pp = sp2 + b * 128;
            s += pp[tid]; q += pp[64 + tid];
        }
        float inv = 1.f / (float)RTOT;
        float mean = s * inv;
        float var  = q * inv - mean * mean;
        float a = go[tid] * rsqrtf(var + EPSF);
        CF[tid] = a;
        CF[64 + tid] = beo[tid] - mean * a;
    }
    __syncthreads();
#pragma unroll
    for (int ct = 0; ct < 2; ct++) {
        int cc = ct * 32 + ln;
        float a = CF[cc], b = CF[64 + cc];
#pragma unroll
        for (int r = 0; r < 16; r++) {
            int row = rbase + wv*32 + (r & 3) + 8 * (r >> 2) + 4 * hi;
            out[(size_t)row * 64 + cc] = fmaxf(a * acco[ct][r] + b, 0.f);
        }
    }
}

// ===========================================================================
// FALLBACK (R12-proven pipeline) — used only if the cooperative mega launch
// is rejected. Verbatim from Round 12.
// ===========================================================================
__global__ __launch_bounds__(256) void fb_gemm_qkv(
        const float* __restrict__ Qin, const float* __restrict__ Kin,
        const float* __restrict__ mask,
        const float* __restrict__ Wq, const float* __restrict__ bq,
        const float* __restrict__ Wk, const float* __restrict__ bk,
        const float* __restrict__ Wv, const float* __restrict__ bv,
        _Float16* __restrict__ Yq, _Float16* __restrict__ Yk,
        _Float16* __restrict__ Vr, _Float16* __restrict__ zt,
        float* __restrict__ stats) {
    __shared__ char WT[8192];
    __shared__ _Float16 YT[256 * 72];
    __shared__ float red[128];
    int tid = threadIdx.x;
    int which = blockIdx.y;
    const float* X    = which ? Kin : Qin;
    const float* W    = which == 0 ? Wq : (which == 1 ? Wk : Wv);
    const float* bias = which == 0 ? bq : (which == 1 ? bk : bv);
    float* st = stats + which * 128;

    for (int i = tid; i < 4096; i += 256) {
        int d = i >> 6, e = i & 63;
        int off = ((e * 64 + d) * 2) ^ ((e & 7) << 4);
        *(_Float16*)(&WT[off]) = (_Float16)W[i];
    }
    if (tid < 128) red[tid] = 0.f;

    int wvi = tid >> 6, lane = tid & 63, ln = lane & 31, hi = lane >> 5;
    int rbase = blockIdx.x * 256 + wvi * 64;

    half8 af[2][4];
#pragma unroll
    for (int rt = 0; rt < 2; rt++)
#pragma unroll
        for (int kc = 0; kc < 4; kc++)
            af[rt][kc] = ldaf(X, (size_t)(rbase + rt*32 + ln) * 64 + kc*16 + 8*hi);

    if (which == 0) {
        int row = blockIdx.x * 256 + tid;
        const float4* mr = (const float4*)(mask + (size_t)row * 64);
        float s[8];
#pragma unroll
        for (int h8 = 0; h8 < 8; h8++) s[h8] = 0.f;
#pragma unroll
        for (int i = 0; i < 16; i++) {
            float4 m = mr[i];
            s[i >> 1] += m.x + m.y + m.z + m.w;
        }
#pragma unroll
        for (int h8 = 0; h8 < 8; h8++)
            zt[(size_t)h8 * RTOT + row] = (_Float16)((s[h8] == 0.f) ? 0.f : SCQ);
    }
    __syncthreads();

    half8 bf[2][4];
#pragma unroll
    for (int ct = 0; ct < 2; ct++)
#pragma unroll
        for (int kc = 0; kc < 4; kc++)
            bf[ct][kc] = ldbf(WT, ct * 32 + ln, kc * 16 + 8 * hi);

    f32x16 acc[2][2];
#pragma unroll
    for (int rt = 0; rt < 2; rt++)
#pragma unroll
        for (int ct = 0; ct < 2; ct++) {
#pragma unroll
            for (int r = 0; r < 16; r++) acc[rt][ct][r] = 0.f;
#pragma unroll
            for (int kc = 0; kc < 4; kc++)
                acc[rt][ct] = __builtin_amdgcn_mfma_f32_32x32x16_f16(
                    af[rt][kc], bf[ct][kc], acc[rt][ct], 0, 0, 0);
        }

#pragma unroll
    for (int ct = 0; ct < 2; ct++) {
        int cc = ct * 32 + ln;
        float bv_ = bias[cc];
        float s = 0.f, q = 0.f;
#pragma unroll
        for (int rt = 0; rt < 2; rt++)
#pragma unroll
            for (int r = 0; r < 16; r++) {
                float v = acc[rt][ct][r] + bv_;
                s += v; q += v * v;
                int lrow = wvi*64 + rt*32 + (r & 3) + 8*(r >> 2) + 4*hi;
                YT[lrow * 72 + cc] = (_Float16)v;
            }
        s += __shfl_xor(s, 32, 64);
        q += __shfl_xor(q, 32, 64);
        if (lane < 32) {
            atomicAdd(&red[cc], s);
            atomicAdd(&red[64 + cc], q);
        }
    }
    __syncthreads();
    if (tid < 128) atomicAdd(&st[tid], red[tid]);

    if (which < 2) {
        _Float16* Y = which == 0 ? Yq : Yk;
#pragma unroll
        for (int j = 0; j < 8; j++) {
            int h = j, r = tid;
            half8 v = *(const half8*)&YT[r * 72 + h * 8];
            *(half8*)(Y + ((size_t)h * RTOT + blockIdx.x * 256 + r) * 8) = v;
        }
    } else {
        int chBase = blockIdx.x * 32;
#pragma unroll
        for (int j = 0; j < 8; j++) {
            int idx = j * 256 + tid;
            int h = idx >> 8, rem = idx & 255;
            int ch = rem >> 3, c = rem & 7;
            half8 w;
#pragma unroll
            for (int i = 0; i < 8; i++)
                w[i] = YT[(ch * 8 + i) * 72 + h * 8 + c];
            *(half8*)(Vr + (size_t)h * RT9 + (size_t)(chBase + ch) * 72 + c * 8) = w;
        }
        {
            int h = tid >> 5, ch = tid & 31;
            half8 one8;
#pragma unroll
            for (int i = 0; i < 8; i++) one8[i] = (_Float16)1.0f;
            *(half8*)(Vr + (size_t)h * RT9 + (size_t)(chBase + ch) * 72 + 64) = one8;
        }
    }
}

__global__ __launch_bounds__(512) void fb_attn(
        const _Float16* __restrict__ Yq, const _Float16* __restrict__ Yk,
        const _Float16* __restrict__ Vr, const _Float16* __restrict__ zt,
        const float* __restrict__ stats,
        const float* __restrict__ gq, const float* __restrict__ betaq,
        const float* __restrict__ gk, const float* __restrict__ betak,
        const float* __restrict__ gv, const float* __restrict__ betav,
        _Float16* __restrict__ O) {
    __shared__ __align__(16) _Float16 KL[4096];
    __shared__ __align__(16) _Float16 VS[4608];
    __shared__ __align__(16) _Float16 OL[4096];
    __shared__ float CF[384];

    int p = blockIdx.x;
    int h = p / 96;
    int bt = p - h * 96;
    int row0 = bt * 512;
    int co = h * 8;
    int tid = threadIdx.x;

    if (tid < 192) {
        int s = tid >> 6, c = tid & 63;
        const float* g  = s == 0 ? gq : (s == 1 ? gk : gv);
        const float* be = s == 0 ? betaq : (s == 1 ? betak : betav);
        const float* stp = stats + s * 128;
        float inv = 1.f / (float)RTOT;
        float mean = stp[c] * inv;
        float var  = stp[64 + c] * inv - mean * mean;
        float a = g[c] * rsqrtf(var + EPSF);
        CF[s * 128 + c] = a;
        CF[s * 128 + 64 + c] = be[c] - mean * a;
    }
    __syncthreads();

    const _Float16* Ykh = Yk + ((size_t)h * RTOT + row0) * 8;
    const _Float16* Vrh = Vr + (size_t)h * RT9 + (size_t)(row0 >> 3) * 72;
    const _Float16* Yqh = Yq + ((size_t)h * RTOT + row0) * 8;

    {
        int m = tid;
        half8 y = *(const half8*)(Ykh + m * 8);
        half8 kv;
#pragma unroll
        for (int c = 0; c < 8; c++)
            kv[c] = (_Float16)fmaxf(CF[128 + co + c] * (float)y[c] + CF[192 + co + c], 0.f);
        *(half8*)&KL[m * 8] = kv;
    }
    for (int i = tid; i < 576; i += 512) {
        half8 v = ((const half8*)Vrh)[i];
        int c = i % 9;
        if (c < 8) {
            float a = CF[256 + co + c], b = CF[320 + co + c];
#pragma unroll
            for (int e = 0; e < 8; e++)
                v[e] = (_Float16)fmaxf(a * (float)v[e] + b, 0.f);
        }
        ((half8*)VS)[i] = v;
    }
    __syncthreads();

    int wv = tid >> 6;
    int lane = tid & 63;
    int ln = lane & 31;
    int hi = lane >> 5;

    f32x16 zacc, m12;
#pragma unroll
    for (int r = 0; r < 16; r++) { zacc[r] = 0.f; m12[r] = -12.f; }
    half8 hzero;
#pragma unroll
    for (int i = 0; i < 8; i++) hzero[i] = (_Float16)0.f;

#pragma unroll
    for (int sstep = 0; sstep < 2; sstep++) {
        int si = wv + 8 * sstep;
        int n0 = si * 32;
        half8 qf = hzero;
        if (!hi) {
            half8 y = *(const half8*)(Yqh + (n0 + ln) * 8);
            float zmv = (float)zt[(size_t)h * RTOT + row0 + n0 + ln];
#pragma unroll
            for (int c = 0; c < 8; c++)
                qf[c] = (_Float16)(fmaxf(CF[co + c] * (float)y[c] + CF[64 + co + c], 0.f) * zmv);
        }
        f32x16 acc = zacc;

#pragma unroll 4
        for (int t = 0; t < 16; t++) {
            half8 kf = hzero;
            if (!hi) kf = *(const half8*)&KL[(t * 32 + ln) * 8];
            f32x16 sv = __builtin_amdgcn_mfma_f32_32x32x16_f16(kf, qf, m12, 0, 0, 0);
            float pe[16];
#pragma unroll
            for (int r = 0; r < 16; r++)
                pe[r] = __builtin_amdgcn_exp2f(sv[r]);
#pragma unroll
            for (int ks = 0; ks < 2; ks++) {
                unsigned int x1 = bcu(cvt2h(pe[8*ks+0], pe[8*ks+1]));
                unsigned int x2 = bcu(cvt2h(pe[8*ks+2], pe[8*ks+3]));
                unsigned int y1 = bcu(cvt2h(pe[8*ks+4], pe[8*ks+5]));
                unsigned int y2 = bcu(cvt2h(pe[8*ks+6], pe[8*ks+7]));
                swap32(x1, y1, hi);
                swap32(x2, y2, hi);
                uint4 pw = make_uint4(x1, x2, y1, y2);
                half8 pa = __builtin_bit_cast(half8, pw);
                int chunk = t * 4 + ks * 2 + hi;
                half8 vf = hzero;
                if (ln <= 8) vf = *(const half8*)&VS[chunk * 72 + ln * 8];
                acc = __builtin_amdgcn_mfma_f32_32x32x16_f16(pa, vf, acc, 0, 0, 0);
            }
        }

#pragma unroll
        for (int r = 0; r < 16; r++) {
            float av = acc[r];
            float den = __shfl(av, 8 + 32 * hi, 64);
            float ov = av * __builtin_amdgcn_rcpf(den);
            if (ln < 8) {
                int nrow = n0 + (r & 3) + 8 * (r >> 2) + 4 * hi;
                OL[nrow * 8 + ln] = (_Float16)ov;
            }
        }
    }
    __syncthreads();
    ((uint4*)(O + ((size_t)h * RTOT + row0) * 8))[tid] = ((const uint4*)OL)[tid];
}

__global__ __launch_bounds__(256) void fb_gemm_o_norm(
        const _Float16* __restrict__ X,
        const float* __restrict__ Wo, const float* __restrict__ bo,
        const float* __restrict__ go, const float* __restrict__ betao,
        float* __restrict__ st, float* __restrict__ out) {
    __shared__ char WT[8192];
    __shared__ float red[128];
    __shared__ float CF[128];
    int tid = threadIdx.x;
    for (int i = tid; i < 4096; i += 256) {
        int d = i >> 6, e = i & 63;
        int off = ((e * 64 + d) * 2) ^ ((e & 7) << 4);
        *(_Float16*)(&WT[off]) = (_Float16)Wo[i];
    }
    if (tid < 128) red[tid] = 0.f;

    int wvi = tid >> 6, lane = tid & 63, ln = lane & 31, hi = lane >> 5;
    int rbase = blockIdx.x * 256 + wvi * 64;

    half8 af[2][4];
#pragma unroll
    for (int rt = 0; rt < 2; rt++)
#pragma unroll
        for (int kc = 0; kc < 4; kc++)
            af[rt][kc] = *(const half8*)(X + ((size_t)(2*kc + hi) * RTOT + rbase + rt*32 + ln) * 8);
    __syncthreads();

    half8 bf[2][4];
#pragma unroll
    for (int ct = 0; ct < 2; ct++)
#pragma unroll
        for (int kc = 0; kc < 4; kc++)
            bf[ct][kc] = ldbf(WT, ct * 32 + ln, kc * 16 + 8 * hi);

    f32x16 acc[2][2];
#pragma unroll
    for (int rt = 0; rt < 2; rt++)
#pragma unroll
        for (int ct = 0; ct < 2; ct++) {
#pragma unroll
            for (int r = 0; r < 16; r++) acc[rt][ct][r] = 0.f;
#pragma unroll
            for (int kc = 0; kc < 4; kc++)
                acc[rt][ct] = __builtin_amdgcn_mfma_f32_32x32x16_f16(
                    af[rt][kc], bf[ct][kc], acc[rt][ct], 0, 0, 0);
        }

#pragma unroll
    for (int ct = 0; ct < 2; ct++) {
        float bv_ = bo[ct * 32 + ln];
        float s = 0.f, q = 0.f;
#pragma unroll
        for (int rt = 0; rt < 2; rt++)
#pragma unroll
            for (int r = 0; r < 16; r++) {
                float v = acc[rt][ct][r] + bv_;
                acc[rt][ct][r] = v;
                s += v; q += v * v;
            }
        s += __shfl_xor(s, 32, 64);
        q += __shfl_xor(q, 32, 64);
        if (lane < 32) {
            atomicAdd(&red[ct*32 + ln], s);
            atomicAdd(&red[64 + ct*32 + ln], q);
        }
    }
    __syncthreads();
    if (tid < 128) atomicAdd(&st[tid], red[tid]);

    __threadfence();
    cooperative_groups::this_grid().sync();

    if (tid < 64) {
        float inv = 1.f / (float)RTOT;
        float mean = st[tid] * inv;
        float var  = st[64 + tid] * inv - mean * mean;
        float a = go[tid] * rsqrtf(var + EPSF);
        CF[tid] = a;
        CF[64 + tid] = betao[tid] - mean * a;
    }
    __syncthreads();

#pragma unroll
    for (int ct = 0; ct < 2; ct++) {
        int c = ct * 32 + ln;
        float a = CF[c], b = CF[64 + c];
#pragma unroll
        for (int rt = 0; rt < 2; rt++)
#pragma unroll
            for (int r = 0; r < 16; r++) {
                int row = rbase + rt*32 + (r & 3) + 8*(r >> 2) + 4*hi;
                out[(size_t)row * 64 + c] = fmaxf(a * acc[rt][ct][r] + b, 0.f);
            }
    }
}

extern "C" void kernel_launch(void* const* d_in, const int* in_sizes, int n_in,
                              void* d_out, int out_size, void* d_ws, size_t ws_size,
                              hipStream_t stream) {
    const float* Q    = (const float*)d_in[0];
    const float* Kin  = (const float*)d_in[1];
    const float* mask = (const float*)d_in[2];
    const float* Wq = (const float*)d_in[4];
    const float* bq = (const float*)d_in[5];
    const float* gq = (const float*)d_in[6];
    const float* betaq = (const float*)d_in[7];
    const float* Wk = (const float*)d_in[8];
    const float* bk = (const float*)d_in[9];
    const float* gk = (const float*)d_in[10];
    const float* betak = (const float*)d_in[11];
    const float* Wv = (const float*)d_in[12];
    const float* bv = (const float*)d_in[13];
    const float* gv = (const float*)d_in[14];
    const float* betav = (const float*)d_in[15];
    const float* Wo = (const float*)d_in[16];
    const float* bo = (const float*)d_in[17];
    const float* go = (const float*)d_in[18];
    const float* betao = (const float*)d_in[19];

    const size_t TSZ = (size_t)RTOT * 64;
    _Float16* Qt = (_Float16*)d_ws;
    _Float16* Kt = Qt + TSZ;
    _Float16* Vr = Kt + TSZ;                      // RTOT*72 halfs
    _Float16* Ob = Vr + (size_t)RTOT * 72;
    float* sp1 = (float*)(Ob + TSZ);              // 192*384 floats
    float* sp2 = sp1 + NBLK * 384;                // 192*128 floats
    _Float16* zt = (_Float16*)(sp2 + NBLK * 128); // fallback: 8*RTOT halfs
    float* stats = (float*)(zt + (size_t)8 * RTOT);  // fallback: 512 floats

    float* outp = (float*)d_out;

    const float *Qp = Q, *Kp = Kin, *mp = mask;
    const float *wq = Wq, *bq_ = bq, *gq_ = gq, *aq = betaq;
    const float *wk = Wk, *bk_ = bk, *gk_ = gk, *ak = betak;
    const float *wv = Wv, *bv_ = bv, *gv_ = gv, *av = betav;
    const float *wo = Wo, *bo_ = bo, *go_ = go, *ao = betao;
    _Float16 *qt = Qt, *kt = Kt, *vr = Vr, *ob = Ob;
    float *s1 = sp1, *s2 = sp2;
    void* args[] = { (void*)&Qp, (void*)&Kp, (void*)&mp,
                     (void*)&wq, (void*)&bq_, (void*)&gq_, (void*)&aq,
                     (void*)&wk, (void*)&bk_, (void*)&gk_, (void*)&ak,
                     (void*)&wv, (void*)&bv_, (void*)&gv_, (void*)&av,
                     (void*)&wo, (void*)&bo_, (void*)&go_, (void*)&ao,
                     (void*)&qt, (void*)&kt, (void*)&vr, (void*)&ob,
                     (void*)&s1, (void*)&s2, (void*)&outp };
    hipError_t ce = hipLaunchCooperativeKernel(reinterpret_cast<void*>(&mab_mega),
                                               dim3(NBLK), dim3(512), args, 0, stream);
    if (ce != hipSuccess) {
        // ---- fallback: proven R12 pipeline ----
        (void)hipMemsetAsync(stats, 0, 512 * sizeof(float), stream);
        dim3 gqkv(192, 3);
        fb_gemm_qkv<<<gqkv, 256, 0, stream>>>(Q, Kin, mask, Wq, bq, Wk, bk, Wv, bv,
                                              Qt, Kt, Vr, zt, stats);
        fb_attn<<<768, 512, 0, stream>>>(Qt, Kt, Vr, zt, stats,
                                         gq, betaq, gk, betak, gv, betav, Ob);
        const _Float16* Xo = Ob;
        float* st4 = stats + 384;
        void* args2[] = { (void*)&Xo, (void*)&wo, (void*)&bo_,
                          (void*)&go_, (void*)&ao, (void*)&st4, (void*)&outp };
        (void)hipLaunchCooperativeKernel(reinterpret_cast<void*>(&fb_gemm_o_norm),
                                         dim3(192), dim3(256), args2, 0, stream);
    }
}

// Round 14
// 124.008 us; speedup vs baseline: 2.8102x; 2.8102x over previous
//
#include <hip/hip_runtime.h>
#include <hip/hip_bf16.h>
#include <hip/hip_cooperative_groups.h>

#define RTOT 49152
#define RT9  442368               // (RTOT/8) * 72, V-interleaved per-head stride
#define EPSF 1e-5f
#define SCQ 0.5101062398836783f   // (1/sqrt(8)) * log2(e)

typedef _Float16 h2 __attribute__((ext_vector_type(2)));
typedef _Float16 half8 __attribute__((ext_vector_type(8)));
typedef float f32x16 __attribute__((ext_vector_type(16)));

__device__ __forceinline__ h2 cvt2h(float a, float b) {
    return __builtin_bit_cast(h2, __builtin_amdgcn_cvt_pkrtz(a, b));
}
__device__ __forceinline__ unsigned int bcu(h2 v) { return __builtin_bit_cast(unsigned int, v); }

__device__ __forceinline__ void swap32(unsigned int& x, unsigned int& y, int hi) {
#if __has_builtin(__builtin_amdgcn_permlane32_swap)
    auto r = __builtin_amdgcn_permlane32_swap(x, y, false, false);
    x = r[0]; y = r[1];
#else
    unsigned int xs = (unsigned int)__shfl_xor((int)x, 32, 64);
    unsigned int ys = (unsigned int)__shfl_xor((int)y, 32, 64);
    unsigned int nx = hi ? ys : x;
    unsigned int ny = hi ? y : xs;
    x = nx; y = ny;
#endif
}

__device__ __forceinline__ half8 ldaf(const float* __restrict__ X, size_t base) {
    const float4* p = (const float4*)(X + base);
    float4 x = p[0], y = p[1];
    uint4 u = make_uint4(bcu(cvt2h(x.x, x.y)), bcu(cvt2h(x.z, x.w)),
                         bcu(cvt2h(y.x, y.y)), bcu(cvt2h(y.z, y.w)));
    return __builtin_bit_cast(half8, u);
}
__device__ __forceinline__ half8 ldbf(const char* WT, int e, int k0) {
    int off = ((e * 64 + k0) * 2) ^ ((e & 7) << 4);
    return *(const half8*)(WT + off);
}

// ---------------------------------------------------------------------------
// QKV projection, grid (192,3) x 512 thr (8 waves, 1 row-tile/wave for TLP).
// y = 0/1/2 -> Q/K/V. Raw f16 outputs via LDS transpose YT[256][72]:
//   Q/K head-major [h][row][8]; V pre-interleaved [h][chunk][9][8] + ones.
// zt[h][row] mask table; stats via LDS reduce -> 128 global atomics/block.
// Fragment layout (verified R4-R12): A/B lane&31 = M/N idx, lane>>5 = k-half;
// D row=(r&3)+8(r>>2)+4hi, col=lane&31.
// ---------------------------------------------------------------------------
__global__ __launch_bounds__(512) void gemm_qkv(
        const float* __restrict__ Qin, const float* __restrict__ Kin,
        const float* __restrict__ mask,
        const float* __restrict__ Wq, const float* __restrict__ bq,
        const float* __restrict__ Wk, const float* __restrict__ bk,
        const float* __restrict__ Wv, const float* __restrict__ bv,
        _Float16* __restrict__ Yq, _Float16* __restrict__ Yk,
        _Float16* __restrict__ Vr, _Float16* __restrict__ zt,
        float* __restrict__ stats) {
    __shared__ char WT[8192];
    __shared__ _Float16 YT[256 * 72];
    __shared__ float red[128];
    int tid = threadIdx.x;
    int which = blockIdx.y;
    const float* X    = which ? Kin : Qin;
    const float* W    = which == 0 ? Wq : (which == 1 ? Wk : Wv);
    const float* bias = which == 0 ? bq : (which == 1 ? bk : bv);
    float* st = stats + which * 128;

#pragma unroll
    for (int j = 0; j < 8; j++) {
        int i = j * 512 + tid;
        int d = i >> 6, e = i & 63;
        int off = ((e * 64 + d) * 2) ^ ((e & 7) << 4);
        *(_Float16*)(&WT[off]) = (_Float16)W[i];
    }
    if (tid < 128) red[tid] = 0.f;

    int wvi = tid >> 6, lane = tid & 63, ln = lane & 31, hi = lane >> 5;
    int row = blockIdx.x * 256 + wvi * 32 + ln;

    half8 af[4];
#pragma unroll
    for (int kc = 0; kc < 4; kc++)
        af[kc] = ldaf(X, (size_t)row * 64 + kc * 16 + 8 * hi);

    if (which == 0 && tid < 256) {   // mask row-sum table, coalesced
        int mrow = blockIdx.x * 256 + tid;
        const float4* mr = (const float4*)(mask + (size_t)mrow * 64);
        float s[8];
#pragma unroll
        for (int h8 = 0; h8 < 8; h8++) s[h8] = 0.f;
#pragma unroll
        for (int i = 0; i < 16; i++) {
            float4 m = mr[i];
            s[i >> 1] += m.x + m.y + m.z + m.w;
        }
#pragma unroll
        for (int h8 = 0; h8 < 8; h8++)
            zt[(size_t)h8 * RTOT + mrow] = (_Float16)((s[h8] == 0.f) ? 0.f : SCQ);
    }
    __syncthreads();

    f32x16 acc[2];
#pragma unroll
    for (int ct = 0; ct < 2; ct++) {
#pragma unroll
        for (int r = 0; r < 16; r++) acc[ct][r] = 0.f;
        int e = ct * 32 + ln;
#pragma unroll
        for (int kc = 0; kc < 4; kc++) {
            half8 bf = ldbf(WT, e, kc * 16 + 8 * hi);
            acc[ct] = __builtin_amdgcn_mfma_f32_32x32x16_f16(af[kc], bf, acc[ct], 0, 0, 0);
        }
    }

    // bias + stats partials; raw Y into LDS transpose buffer
#pragma unroll
    for (int ct = 0; ct < 2; ct++) {
        int cc = ct * 32 + ln;
        float bv_ = bias[cc];
        float s = 0.f, q = 0.f;
#pragma unroll
        for (int r = 0; r < 16; r++) {
            float v = acc[ct][r] + bv_;
            s += v; q += v * v;
            int lrow = wvi * 32 + (r & 3) + 8 * (r >> 2) + 4 * hi;
            YT[lrow * 72 + cc] = (_Float16)v;
        }
        s += __shfl_xor(s, 32, 64);
        q += __shfl_xor(q, 32, 64);
        if (lane < 32) {
            atomicAdd(&red[cc], s);
            atomicAdd(&red[64 + cc], q);
        }
    }
    __syncthreads();
    if (tid < 128) atomicAdd(&st[tid], red[tid]);

    // coalesced store phase
    if (which < 2) {
        _Float16* Y = which == 0 ? Yq : Yk;
#pragma unroll
        for (int j = 0; j < 4; j++) {
            int idx = j * 512 + tid;
            int h = idx >> 8, r = idx & 255;
            half8 v = *(const half8*)&YT[r * 72 + h * 8];
            *(half8*)(Y + ((size_t)h * RTOT + blockIdx.x * 256 + r) * 8) = v;
        }
    } else {
        int chBase = blockIdx.x * 32;
#pragma unroll
        for (int j = 0; j < 4; j++) {
            int idx = j * 512 + tid;
            int h = idx >> 8, rem = idx & 255;
            int ch = rem >> 3, c = rem & 7;
            half8 w;
#pragma unroll
            for (int i = 0; i < 8; i++)
                w[i] = YT[(ch * 8 + i) * 72 + h * 8 + c];
            *(half8*)(Vr + (size_t)h * RT9 + (size_t)(chBase + ch) * 72 + c * 8) = w;
        }
        if (tid < 256) {   // ones column (c = 8)
            int h = tid >> 5, ch = tid & 31;
            half8 one8;
#pragma unroll
            for (int i = 0; i < 8; i++) one8[i] = (_Float16)1.0f;
            *(half8*)(Vr + (size_t)h * RT9 + (size_t)(chBase + ch) * 72 + 64) = one8;
        }
    }
}

// ---------------------------------------------------------------------------
// MFMA attention (R12 verbatim): 768 blocks x 512 thr, staging+BN once per
// (head, bt); pre-interleaved V with ones col; O via LDS, coalesced stores.
// ---------------------------------------------------------------------------
__global__ __launch_bounds__(512) void attn_mfma(
        const _Float16* __restrict__ Yq, const _Float16* __restrict__ Yk,
        const _Float16* __restrict__ Vr, const _Float16* __restrict__ zt,
        const float* __restrict__ stats,
        const float* __restrict__ gq, const float* __restrict__ betaq,
        const float* __restrict__ gk, const float* __restrict__ betak,
        const float* __restrict__ gv, const float* __restrict__ betav,
        _Float16* __restrict__ O) {
    __shared__ __align__(16) _Float16 KL[4096];
    __shared__ __align__(16) _Float16 VS[4608];
    __shared__ __align__(16) _Float16 OL[4096];
    __shared__ float CF[384];

    int p = blockIdx.x;
    int h = p / 96;
    int bt = p - h * 96;
    int row0 = bt * 512;
    int co = h * 8;
    int tid = threadIdx.x;

    if (tid < 192) {
        int s = tid >> 6, c = tid & 63;
        const float* g  = s == 0 ? gq : (s == 1 ? gk : gv);
        const float* be = s == 0 ? betaq : (s == 1 ? betak : betav);
        const float* stp = stats + s * 128;
        float inv = 1.f / (float)RTOT;
        float mean = stp[c] * inv;
        float var  = stp[64 + c] * inv - mean * mean;
        float a = g[c] * rsqrtf(var + EPSF);
        CF[s * 128 + c] = a;
        CF[s * 128 + 64 + c] = be[c] - mean * a;
    }
    __syncthreads();

    const _Float16* Ykh = Yk + ((size_t)h * RTOT + row0) * 8;
    const _Float16* Vrh = Vr + (size_t)h * RT9 + (size_t)(row0 >> 3) * 72;
    const _Float16* Yqh = Yq + ((size_t)h * RTOT + row0) * 8;

    {
        int m = tid;
        half8 y = *(const half8*)(Ykh + m * 8);
        half8 kv;
#pragma unroll
        for (int c = 0; c < 8; c++)
            kv[c] = (_Float16)fmaxf(CF[128 + co + c] * (float)y[c] + CF[192 + co + c], 0.f);
        *(half8*)&KL[m * 8] = kv;
    }
    for (int i = tid; i < 576; i += 512) {
        half8 v = ((const half8*)Vrh)[i];
        int c = i % 9;
        if (c < 8) {
            float a = CF[256 + co + c], b = CF[320 + co + c];
#pragma unroll
            for (int e = 0; e < 8; e++)
                v[e] = (_Float16)fmaxf(a * (float)v[e] + b, 0.f);
        }
        ((half8*)VS)[i] = v;
    }
    __syncthreads();

    int wv = tid >> 6;
    int lane = tid & 63;
    int ln = lane & 31;
    int hi = lane >> 5;

    f32x16 zacc, m12;
#pragma unroll
    for (int r = 0; r < 16; r++) { zacc[r] = 0.f; m12[r] = -12.f; }
    half8 hzero;
#pragma unroll
    for (int i = 0; i < 8; i++) hzero[i] = (_Float16)0.f;

#pragma unroll
    for (int sstep = 0; sstep < 2; sstep++) {
        int si = wv + 8 * sstep;
        int n0 = si * 32;
        half8 qf = hzero;
        if (!hi) {
            half8 y = *(const half8*)(Yqh + (n0 + ln) * 8);
            float zmv = (float)zt[(size_t)h * RTOT + row0 + n0 + ln];
#pragma unroll
            for (int c = 0; c < 8; c++)
                qf[c] = (_Float16)(fmaxf(CF[co + c] * (float)y[c] + CF[64 + co + c], 0.f) * zmv);
        }
        f32x16 acc = zacc;

#pragma unroll 4
        for (int t = 0; t < 16; t++) {
            half8 kf = hzero;
            if (!hi) kf = *(const half8*)&KL[(t * 32 + ln) * 8];
            f32x16 sv = __builtin_amdgcn_mfma_f32_32x32x16_f16(kf, qf, m12, 0, 0, 0);
            float pe[16];
#pragma unroll
            for (int r = 0; r < 16; r++)
                pe[r] = __builtin_amdgcn_exp2f(sv[r]);
#pragma unroll
            for (int ks = 0; ks < 2; ks++) {
                unsigned int x1 = bcu(cvt2h(pe[8*ks+0], pe[8*ks+1]));
                unsigned int x2 = bcu(cvt2h(pe[8*ks+2], pe[8*ks+3]));
                unsigned int y1 = bcu(cvt2h(pe[8*ks+4], pe[8*ks+5]));
                unsigned int y2 = bcu(cvt2h(pe[8*ks+6], pe[8*ks+7]));
                swap32(x1, y1, hi);
                swap32(x2, y2, hi);
                uint4 pw = make_uint4(x1, x2, y1, y2);
                half8 pa = __builtin_bit_cast(half8, pw);
                int chunk = t * 4 + ks * 2 + hi;
                half8 vf = hzero;
                if (ln <= 8) vf = *(const half8*)&VS[chunk * 72 + ln * 8];
                acc = __builtin_amdgcn_mfma_f32_32x32x16_f16(pa, vf, acc, 0, 0, 0);
            }
        }

#pragma unroll
        for (int r = 0; r < 16; r++) {
            float av = acc[r];
            float den = __shfl(av, 8 + 32 * hi, 64);
            float ov = av * __builtin_amdgcn_rcpf(den);
            if (ln < 8) {
                int nrow = n0 + (r & 3) + 8 * (r >> 2) + 4 * hi;
                OL[nrow * 8 + ln] = (_Float16)ov;
            }
        }
    }
    __syncthreads();
    ((uint4*)(O + ((size_t)h * RTOT + row0) * 8))[tid] = ((const uint4*)OL)[tid];
}

// ---------------------------------------------------------------------------
// Cooperative O-projection + BN-ReLU, 512-thread variant (8 waves for TLP).
// 192 blocks -> co-residency safe (<= 1 block/CU). Error-checked at launch;
// falls back to the R12-proven 256-thread version below.
// ---------------------------------------------------------------------------
__global__ __launch_bounds__(512) void gemm_o_norm512(
        const _Float16* __restrict__ X,
        const float* __restrict__ Wo, const float* __restrict__ bo,
        const float* __restrict__ go, const float* __restrict__ betao,
        float* __restrict__ st, float* __restrict__ out) {
    __shared__ char WT[8192];
    __shared__ float red[128];
    __shared__ float CF[128];
    int tid = threadIdx.x;
#pragma unroll
    for (int j = 0; j < 8; j++) {
        int i = j * 512 + tid;
        int d = i >> 6, e = i & 63;
        int off = ((e * 64 + d) * 2) ^ ((e & 7) << 4);
        *(_Float16*)(&WT[off]) = (_Float16)Wo[i];
    }
    if (tid < 128) red[tid] = 0.f;

    int wvi = tid >> 6, lane = tid & 63, ln = lane & 31, hi = lane >> 5;
    int rowBase = blockIdx.x * 256 + wvi * 32;

    half8 af[4];
#pragma unroll
    for (int kc = 0; kc < 4; kc++)
        af[kc] = *(const half8*)(X + ((size_t)(2*kc + hi) * RTOT + rowBase + ln) * 8);
    __syncthreads();

    f32x16 acc[2];
#pragma unroll
    for (int ct = 0; ct < 2; ct++) {
#pragma unroll
        for (int r = 0; r < 16; r++) acc[ct][r] = 0.f;
        int e = ct * 32 + ln;
#pragma unroll
        for (int kc = 0; kc < 4; kc++) {
            half8 bf = ldbf(WT, e, kc * 16 + 8 * hi);
            acc[ct] = __builtin_amdgcn_mfma_f32_32x32x16_f16(af[kc], bf, acc[ct], 0, 0, 0);
        }
    }

#pragma unroll
    for (int ct = 0; ct < 2; ct++) {
        int cc = ct * 32 + ln;
        float bv_ = bo[cc];
        float s = 0.f, q = 0.f;
#pragma unroll
        for (int r = 0; r < 16; r++) {
            float v = acc[ct][r] + bv_;
            acc[ct][r] = v;
            s += v; q += v * v;
        }
        s += __shfl_xor(s, 32, 64);
        q += __shfl_xor(q, 32, 64);
        if (lane < 32) {
            atomicAdd(&red[cc], s);
            atomicAdd(&red[64 + cc], q);
        }
    }
    __syncthreads();
    if (tid < 128) atomicAdd(&st[tid], red[tid]);

    __threadfence();
    cooperative_groups::this_grid().sync();

    if (tid < 64) {
        float inv = 1.f / (float)RTOT;
        float mean = st[tid] * inv;
        float var  = st[64 + tid] * inv - mean * mean;
        float a = go[tid] * rsqrtf(var + EPSF);
        CF[tid] = a;
        CF[64 + tid] = betao[tid] - mean * a;
    }
    __syncthreads();

#pragma unroll
    for (int ct = 0; ct < 2; ct++) {
        int cc = ct * 32 + ln;
        float a = CF[cc], b = CF[64 + cc];
#pragma unroll
        for (int r = 0; r < 16; r++) {
            int row = rowBase + (r & 3) + 8 * (r >> 2) + 4 * hi;
            out[(size_t)row * 64 + cc] = fmaxf(a * acc[ct][r] + b, 0.f);
        }
    }
}

// R12-proven 256-thread fallback
__global__ __launch_bounds__(256) void gemm_o_norm256(
        const _Float16* __restrict__ X,
        const float* __restrict__ Wo, const float* __restrict__ bo,
        const float* __restrict__ go, const float* __restrict__ betao,
        float* __restrict__ st, float* __restrict__ out) {
    __shared__ char WT[8192];
    __shared__ float red[128];
    __shared__ float CF[128];
    int tid = threadIdx.x;
    for (int i = tid; i < 4096; i += 256) {
        int d = i >> 6, e = i & 63;
        int off = ((e * 64 + d) * 2) ^ ((e & 7) << 4);
        *(_Float16*)(&WT[off]) = (_Float16)Wo[i];
    }
    if (tid < 128) red[tid] = 0.f;

    int wvi = tid >> 6, lane = tid & 63, ln = lane & 31, hi = lane >> 5;
    int rbase = blockIdx.x * 256 + wvi * 64;

    half8 af[2][4];
#pragma unroll
    for (int rt = 0; rt < 2; rt++)
#pragma unroll
        for (int kc = 0; kc < 4; kc++)
            af[rt][kc] = *(const half8*)(X + ((size_t)(2*kc + hi) * RTOT + rbase + rt*32 + ln) * 8);
    __syncthreads();

    half8 bf[2][4];
#pragma unroll
    for (int ct = 0; ct < 2; ct++)
#pragma unroll
        for (int kc = 0; kc < 4; kc++)
            bf[ct][kc] = ldbf(WT, ct * 32 + ln, kc * 16 + 8 * hi);

    f32x16 acc[2][2];
#pragma unroll
    for (int rt = 0; rt < 2; rt++)
#pragma unroll
        for (int ct = 0; ct < 2; ct++) {
#pragma unroll
            for (int r = 0; r < 16; r++) acc[rt][ct][r] = 0.f;
#pragma unroll
            for (int kc = 0; kc < 4; kc++)
                acc[rt][ct] = __builtin_amdgcn_mfma_f32_32x32x16_f16(
                    af[rt][kc], bf[ct][kc], acc[rt][ct], 0, 0, 0);
        }

#pragma unroll
    for (int ct = 0; ct < 2; ct++) {
        float bv_ = bo[ct * 32 + ln];
        float s = 0.f, q = 0.f;
#pragma unroll
        for (int rt = 0; rt < 2; rt++)
#pragma unroll
            for (int r = 0; r < 16; r++) {
                float v = acc[rt][ct][r] + bv_;
                acc[rt][ct][r] = v;
                s += v; q += v * v;
            }
        s += __shfl_xor(s, 32, 64);
        q += __shfl_xor(q, 32, 64);
        if (lane < 32) {
            atomicAdd(&red[ct*32 + ln], s);
            atomicAdd(&red[64 + ct*32 + ln], q);
        }
    }
    __syncthreads();
    if (tid < 128) atomicAdd(&st[tid], red[tid]);

    __threadfence();
    cooperative_groups::this_grid().sync();

    if (tid < 64) {
        float inv = 1.f / (float)RTOT;
        float mean = st[tid] * inv;
        float var  = st[64 + tid] * inv - mean * mean;
        float a = go[tid] * rsqrtf(var + EPSF);
        CF[tid] = a;
        CF[64 + tid] = betao[tid] - mean * a;
    }
    __syncthreads();

#pragma unroll
    for (int ct = 0; ct < 2; ct++) {
        int c = ct * 32 + ln;
        float a = CF[c], b = CF[64 + c];
#pragma unroll
        for (int rt = 0; rt < 2; rt++)
#pragma unroll
            for (int r = 0; r < 16; r++) {
                int row = rbase + rt*32 + (r & 3) + 8*(r >> 2) + 4*hi;
                out[(size_t)row * 64 + c] = fmaxf(a * acc[rt][ct][r] + b, 0.f);
            }
    }
}

extern "C" void kernel_launch(void* const* d_in, const int* in_sizes, int n_in,
                              void* d_out, int out_size, void* d_ws, size_t ws_size,
                              hipStream_t stream) {
    const float* Q    = (const float*)d_in[0];
    const float* Kin  = (const float*)d_in[1];
    const float* mask = (const float*)d_in[2];
    const float* Wq = (const float*)d_in[4];
    const float* bq = (const float*)d_in[5];
    const float* gq = (const float*)d_in[6];
    const float* betaq = (const float*)d_in[7];
    const float* Wk = (const float*)d_in[8];
    const float* bk = (const float*)d_in[9];
    const float* gk = (const float*)d_in[10];
    const float* betak = (const float*)d_in[11];
    const float* Wv = (const float*)d_in[12];
    const float* bv = (const float*)d_in[13];
    const float* gv = (const float*)d_in[14];
    const float* betav = (const float*)d_in[15];
    const float* Wo = (const float*)d_in[16];
    const float* bo = (const float*)d_in[17];
    const float* go = (const float*)d_in[18];
    const float* betao = (const float*)d_in[19];

    const size_t TSZ = (size_t)RTOT * 64;
    _Float16* Yq = (_Float16*)d_ws;               // raw head-major
    _Float16* Yk = Yq + TSZ;
    _Float16* Vr = Yk + TSZ;                      // raw pre-interleaved, RTOT*72
    _Float16* Ob = Vr + (size_t)RTOT * 72;
    _Float16* zt = Ob + TSZ;                      // 8 * RTOT halfs
    float* stats = (float*)(zt + (size_t)8 * RTOT);  // 512 floats

    (void)hipMemsetAsync(stats, 0, 512 * sizeof(float), stream);

    dim3 gqkv(192, 3);
    gemm_qkv<<<gqkv, 512, 0, stream>>>(Q, Kin, mask, Wq, bq, Wk, bk, Wv, bv,
                                       Yq, Yk, Vr, zt, stats);

    attn_mfma<<<768, 512, 0, stream>>>(Yq, Yk, Vr, zt, stats,
                                       gq, betaq, gk, betak, gv, betav, Ob);

    {
        const _Float16* Xo = Ob;
        float* st4 = stats + 384;
        float* outp = (float*)d_out;
        const float *wo = Wo, *bo_ = bo, *go_ = go, *ao = betao;
        void* args[] = { (void*)&Xo, (void*)&wo, (void*)&bo_,
                         (void*)&go_, (void*)&ao, (void*)&st4, (void*)&outp };
        hipError_t ce = hipLaunchCooperativeKernel(
            reinterpret_cast<void*>(&gemm_o_norm512),
            dim3(192), dim3(512), args, 0, stream);
        if (ce != hipSuccess) {
            (void)hipLaunchCooperativeKernel(
                reinterpret_cast<void*>(&gemm_o_norm256),
                dim3(192), dim3(256), args, 0, stream);
        }
    }
}

// Round 16
// 78.195 us; speedup vs baseline: 4.4567x; 1.5859x over previous
//
#include <hip/hip_runtime.h>
#include <hip/hip_bf16.h>

#define RTOT 49152
#define RT9  442368               // (RTOT/8) * 72, V-interleaved per-head stride
#define EPSF 1e-5f
#define SCQ 0.5101062398836783f   // (1/sqrt(8)) * log2(e)

typedef _Float16 h2 __attribute__((ext_vector_type(2)));
typedef _Float16 half8 __attribute__((ext_vector_type(8)));
typedef float f32x16 __attribute__((ext_vector_type(16)));

__device__ __forceinline__ h2 cvt2h(float a, float b) {
    return __builtin_bit_cast(h2, __builtin_amdgcn_cvt_pkrtz(a, b));
}
__device__ __forceinline__ unsigned int bcu(h2 v) { return __builtin_bit_cast(unsigned int, v); }

__device__ __forceinline__ void swap32(unsigned int& x, unsigned int& y, int hi) {
#if __has_builtin(__builtin_amdgcn_permlane32_swap)
    auto r = __builtin_amdgcn_permlane32_swap(x, y, false, false);
    x = r[0]; y = r[1];
#else
    unsigned int xs = (unsigned int)__shfl_xor((int)x, 32, 64);
    unsigned int ys = (unsigned int)__shfl_xor((int)y, 32, 64);
    unsigned int nx = hi ? ys : x;
    unsigned int ny = hi ? y : xs;
    x = nx; y = ny;
#endif
}

__device__ __forceinline__ half8 ldaf(const float* __restrict__ X, size_t base) {
    const float4* p = (const float4*)(X + base);
    float4 x = p[0], y = p[1];
    uint4 u = make_uint4(bcu(cvt2h(x.x, x.y)), bcu(cvt2h(x.z, x.w)),
                         bcu(cvt2h(y.x, y.y)), bcu(cvt2h(y.z, y.w)));
    return __builtin_bit_cast(half8, u);
}
__device__ __forceinline__ half8 ldbf(const char* WT, int e, int k0) {
    int off = ((e * 64 + k0) * 2) ^ ((e & 7) << 4);
    return *(const half8*)(WT + off);
}

// ---------------------------------------------------------------------------
// QKV projection (R14-proven), grid (192,3) x 512 thr, 1 row-tile/wave.
// Raw f16 outputs via LDS transpose: Q/K head-major [h][row][8];
// V pre-interleaved [h][chunk][9][8] + ones. zt mask table; stats via LDS
// reduce -> 128 global atomics/block. Fragment layout (verified R4-R14).
// ---------------------------------------------------------------------------
__global__ __launch_bounds__(512) void gemm_qkv(
        const float* __restrict__ Qin, const float* __restrict__ Kin,
        const float* __restrict__ mask,
        const float* __restrict__ Wq, const float* __restrict__ bq,
        const float* __restrict__ Wk, const float* __restrict__ bk,
        const float* __restrict__ Wv, const float* __restrict__ bv,
        _Float16* __restrict__ Yq, _Float16* __restrict__ Yk,
        _Float16* __restrict__ Vr, _Float16* __restrict__ zt,
        float* __restrict__ stats) {
    __shared__ char WT[8192];
    __shared__ _Float16 YT[256 * 72];
    __shared__ float red[128];
    int tid = threadIdx.x;
    int which = blockIdx.y;
    const float* X    = which ? Kin : Qin;
    const float* W    = which == 0 ? Wq : (which == 1 ? Wk : Wv);
    const float* bias = which == 0 ? bq : (which == 1 ? bk : bv);
    float* st = stats + which * 128;

#pragma unroll
    for (int j = 0; j < 8; j++) {
        int i = j * 512 + tid;
        int d = i >> 6, e = i & 63;
        int off = ((e * 64 + d) * 2) ^ ((e & 7) << 4);
        *(_Float16*)(&WT[off]) = (_Float16)W[i];
    }
    if (tid < 128) red[tid] = 0.f;

    int wvi = tid >> 6, lane = tid & 63, ln = lane & 31, hi = lane >> 5;
    int row = blockIdx.x * 256 + wvi * 32 + ln;

    half8 af[4];
#pragma unroll
    for (int kc = 0; kc < 4; kc++)
        af[kc] = ldaf(X, (size_t)row * 64 + kc * 16 + 8 * hi);

    if (which == 0 && tid < 256) {
        int mrow = blockIdx.x * 256 + tid;
        const float4* mr = (const float4*)(mask + (size_t)mrow * 64);
        float s[8];
#pragma unroll
        for (int h8 = 0; h8 < 8; h8++) s[h8] = 0.f;
#pragma unroll
        for (int i = 0; i < 16; i++) {
            float4 m = mr[i];
            s[i >> 1] += m.x + m.y + m.z + m.w;
        }
#pragma unroll
        for (int h8 = 0; h8 < 8; h8++)
            zt[(size_t)h8 * RTOT + mrow] = (_Float16)((s[h8] == 0.f) ? 0.f : SCQ);
    }
    __syncthreads();

    f32x16 acc[2];
#pragma unroll
    for (int ct = 0; ct < 2; ct++) {
#pragma unroll
        for (int r = 0; r < 16; r++) acc[ct][r] = 0.f;
        int e = ct * 32 + ln;
#pragma unroll
        for (int kc = 0; kc < 4; kc++) {
            half8 bf = ldbf(WT, e, kc * 16 + 8 * hi);
            acc[ct] = __builtin_amdgcn_mfma_f32_32x32x16_f16(af[kc], bf, acc[ct], 0, 0, 0);
        }
    }

#pragma unroll
    for (int ct = 0; ct < 2; ct++) {
        int cc = ct * 32 + ln;
        float bv_ = bias[cc];
        float s = 0.f, q = 0.f;
#pragma unroll
        for (int r = 0; r < 16; r++) {
            float v = acc[ct][r] + bv_;
            s += v; q += v * v;
            int lrow = wvi * 32 + (r & 3) + 8 * (r >> 2) + 4 * hi;
            YT[lrow * 72 + cc] = (_Float16)v;
        }
        s += __shfl_xor(s, 32, 64);
        q += __shfl_xor(q, 32, 64);
        if (lane < 32) {
            atomicAdd(&red[cc], s);
            atomicAdd(&red[64 + cc], q);
        }
    }
    __syncthreads();
    if (tid < 128) atomicAdd(&st[tid], red[tid]);

    if (which < 2) {
        _Float16* Y = which == 0 ? Yq : Yk;
#pragma unroll
        for (int j = 0; j < 4; j++) {
            int idx = j * 512 + tid;
            int h = idx >> 8, r = idx & 255;
            half8 v = *(const half8*)&YT[r * 72 + h * 8];
            *(half8*)(Y + ((size_t)h * RTOT + blockIdx.x * 256 + r) * 8) = v;
        }
    } else {
        int chBase = blockIdx.x * 32;
#pragma unroll
        for (int j = 0; j < 4; j++) {
            int idx = j * 512 + tid;
            int h = idx >> 8, rem = idx & 255;
            int ch = rem >> 3, c = rem & 7;
            half8 w;
#pragma unroll
            for (int i = 0; i < 8; i++)
                w[i] = YT[(ch * 8 + i) * 72 + h * 8 + c];
            *(half8*)(Vr + (size_t)h * RT9 + (size_t)(chBase + ch) * 72 + c * 8) = w;
        }
        if (tid < 256) {
            int h = tid >> 5, ch = tid & 31;
            half8 one8;
#pragma unroll
            for (int i = 0; i < 8; i++) one8[i] = (_Float16)1.0f;
            *(half8*)(Vr + (size_t)h * RT9 + (size_t)(chBase + ch) * 72 + 64) = one8;
        }
    }
}

// ---------------------------------------------------------------------------
// MFMA attention (R12-proven verbatim): 768 blocks x 512 thr.
// ---------------------------------------------------------------------------
__global__ __launch_bounds__(512) void attn_mfma(
        const _Float16* __restrict__ Yq, const _Float16* __restrict__ Yk,
        const _Float16* __restrict__ Vr, const _Float16* __restrict__ zt,
        const float* __restrict__ stats,
        const float* __restrict__ gq, const float* __restrict__ betaq,
        const float* __restrict__ gk, const float* __restrict__ betak,
        const float* __restrict__ gv, const float* __restrict__ betav,
        _Float16* __restrict__ O) {
    __shared__ __align__(16) _Float16 KL[4096];
    __shared__ __align__(16) _Float16 VS[4608];
    __shared__ __align__(16) _Float16 OL[4096];
    __shared__ float CF[384];

    int p = blockIdx.x;
    int h = p / 96;
    int bt = p - h * 96;
    int row0 = bt * 512;
    int co = h * 8;
    int tid = threadIdx.x;

    if (tid < 192) {
        int s = tid >> 6, c = tid & 63;
        const float* g  = s == 0 ? gq : (s == 1 ? gk : gv);
        const float* be = s == 0 ? betaq : (s == 1 ? betak : betav);
        const float* stp = stats + s * 128;
        float inv = 1.f / (float)RTOT;
        float mean = stp[c] * inv;
        float var  = stp[64 + c] * inv - mean * mean;
        float a = g[c] * rsqrtf(var + EPSF);
        CF[s * 128 + c] = a;
        CF[s * 128 + 64 + c] = be[c] - mean * a;
    }
    __syncthreads();

    const _Float16* Ykh = Yk + ((size_t)h * RTOT + row0) * 8;
    const _Float16* Vrh = Vr + (size_t)h * RT9 + (size_t)(row0 >> 3) * 72;
    const _Float16* Yqh = Yq + ((size_t)h * RTOT + row0) * 8;

    {
        int m = tid;
        half8 y = *(const half8*)(Ykh + m * 8);
        half8 kv;
#pragma unroll
        for (int c = 0; c < 8; c++)
            kv[c] = (_Float16)fmaxf(CF[128 + co + c] * (float)y[c] + CF[192 + co + c], 0.f);
        *(half8*)&KL[m * 8] = kv;
    }
    for (int i = tid; i < 576; i += 512) {
        half8 v = ((const half8*)Vrh)[i];
        int c = i % 9;
        if (c < 8) {
            float a = CF[256 + co + c], b = CF[320 + co + c];
#pragma unroll
            for (int e = 0; e < 8; e++)
                v[e] = (_Float16)fmaxf(a * (float)v[e] + b, 0.f);
        }
        ((half8*)VS)[i] = v;
    }
    __syncthreads();

    int wv = tid >> 6;
    int lane = tid & 63;
    int ln = lane & 31;
    int hi = lane >> 5;

    f32x16 zacc, m12;
#pragma unroll
    for (int r = 0; r < 16; r++) { zacc[r] = 0.f; m12[r] = -12.f; }
    half8 hzero;
#pragma unroll
    for (int i = 0; i < 8; i++) hzero[i] = (_Float16)0.f;

#pragma unroll
    for (int sstep = 0; sstep < 2; sstep++) {
        int si = wv + 8 * sstep;
        int n0 = si * 32;
        half8 qf = hzero;
        if (!hi) {
            half8 y = *(const half8*)(Yqh + (n0 + ln) * 8);
            float zmv = (float)zt[(size_t)h * RTOT + row0 + n0 + ln];
#pragma unroll
            for (int c = 0; c < 8; c++)
                qf[c] = (_Float16)(fmaxf(CF[co + c] * (float)y[c] + CF[64 + co + c], 0.f) * zmv);
        }
        f32x16 acc = zacc;

#pragma unroll 4
        for (int t = 0; t < 16; t++) {
            half8 kf = hzero;
            if (!hi) kf = *(const half8*)&KL[(t * 32 + ln) * 8];
            f32x16 sv = __builtin_amdgcn_mfma_f32_32x32x16_f16(kf, qf, m12, 0, 0, 0);
            float pe[16];
#pragma unroll
            for (int r = 0; r < 16; r++)
                pe[r] = __builtin_amdgcn_exp2f(sv[r]);
#pragma unroll
            for (int ks = 0; ks < 2; ks++) {
                unsigned int x1 = bcu(cvt2h(pe[8*ks+0], pe[8*ks+1]));
                unsigned int x2 = bcu(cvt2h(pe[8*ks+2], pe[8*ks+3]));
                unsigned int y1 = bcu(cvt2h(pe[8*ks+4], pe[8*ks+5]));
                unsigned int y2 = bcu(cvt2h(pe[8*ks+6], pe[8*ks+7]));
                swap32(x1, y1, hi);
                swap32(x2, y2, hi);
                uint4 pw = make_uint4(x1, x2, y1, y2);
                half8 pa = __builtin_bit_cast(half8, pw);
                int chunk = t * 4 + ks * 2 + hi;
                half8 vf = hzero;
                if (ln <= 8) vf = *(const half8*)&VS[chunk * 72 + ln * 8];
                acc = __builtin_amdgcn_mfma_f32_32x32x16_f16(pa, vf, acc, 0, 0, 0);
            }
        }

#pragma unroll
        for (int r = 0; r < 16; r++) {
            float av = acc[r];
            float den = __shfl(av, 8 + 32 * hi, 64);
            float ov = av * __builtin_amdgcn_rcpf(den);
            if (ln < 8) {
                int nrow = n0 + (r & 3) + 8 * (r >> 2) + 4 * hi;
                OL[nrow * 8 + ln] = (_Float16)ov;
            }
        }
    }
    __syncthreads();
    ((uint4*)(O + ((size_t)h * RTOT + row0) * 8))[tid] = ((const uint4*)OL)[tid];
}

// ---------------------------------------------------------------------------
// O-projection GEMM (non-coop), 192 x 512: GEMM + stats atomics; Yo written
// [row][64] f16 via LDS-transpose coalesced stores. No grid.sync.
// ---------------------------------------------------------------------------
__global__ __launch_bounds__(512) void gemm_o(
        const _Float16* __restrict__ X,
        const float* __restrict__ Wo, const float* __restrict__ bo,
        _Float16* __restrict__ Yo, float* __restrict__ st) {
    __shared__ char WT[8192];
    __shared__ _Float16 YT[256 * 72];
    __shared__ float red[128];
    int tid = threadIdx.x;
#pragma unroll
    for (int j = 0; j < 8; j++) {
        int i = j * 512 + tid;
        int d = i >> 6, e = i & 63;
        int off = ((e * 64 + d) * 2) ^ ((e & 7) << 4);
        *(_Float16*)(&WT[off]) = (_Float16)Wo[i];
    }
    if (tid < 128) red[tid] = 0.f;

    int wvi = tid >> 6, lane = tid & 63, ln = lane & 31, hi = lane >> 5;
    int rowBase = blockIdx.x * 256 + wvi * 32;

    half8 af[4];
#pragma unroll
    for (int kc = 0; kc < 4; kc++)
        af[kc] = *(const half8*)(X + ((size_t)(2*kc + hi) * RTOT + rowBase + ln) * 8);
    __syncthreads();

    f32x16 acc[2];
#pragma unroll
    for (int ct = 0; ct < 2; ct++) {
#pragma unroll
        for (int r = 0; r < 16; r++) acc[ct][r] = 0.f;
        int e = ct * 32 + ln;
#pragma unroll
        for (int kc = 0; kc < 4; kc++) {
            half8 bf = ldbf(WT, e, kc * 16 + 8 * hi);
            acc[ct] = __builtin_amdgcn_mfma_f32_32x32x16_f16(af[kc], bf, acc[ct], 0, 0, 0);
        }
    }

#pragma unroll
    for (int ct = 0; ct < 2; ct++) {
        int cc = ct * 32 + ln;
        float bv_ = bo[cc];
        float s = 0.f, q = 0.f;
#pragma unroll
        for (int r = 0; r < 16; r++) {
            float v = acc[ct][r] + bv_;
            s += v; q += v * v;
            int lrow = wvi * 32 + (r & 3) + 8 * (r >> 2) + 4 * hi;
            YT[lrow * 72 + cc] = (_Float16)v;
        }
        s += __shfl_xor(s, 32, 64);
        q += __shfl_xor(q, 32, 64);
        if (lane < 32) {
            atomicAdd(&red[cc], s);
            atomicAdd(&red[64 + cc], q);
        }
    }
    __syncthreads();
    if (tid < 128) atomicAdd(&st[tid], red[tid]);

    // coalesced [row][64] stores: 2048 half8s
#pragma unroll
    for (int j = 0; j < 4; j++) {
        int idx = j * 512 + tid;
        int r = idx >> 3, c8 = idx & 7;
        half8 v = *(const half8*)&YT[r * 72 + c8 * 8];
        *(half8*)(Yo + ((size_t)(blockIdx.x * 256 + r) * 64 + c8 * 8)) = v;
    }
}

// ---------------------------------------------------------------------------
// BN-ReLU from raw stats (R6-proven): grid 1536 x 256, one half8 per thread.
// ---------------------------------------------------------------------------
__global__ __launch_bounds__(256) void norm_relu16(const _Float16* __restrict__ Y,
                                                   const float* __restrict__ st,
                                                   const float* __restrict__ g,
                                                   const float* __restrict__ be,
                                                   float* __restrict__ out) {
    __shared__ float CF[128];
    int tid = threadIdx.x;
    if (tid < 64) {
        float inv = 1.f / (float)RTOT;
        float mean = st[tid] * inv;
        float var  = st[64 + tid] * inv - mean * mean;
        float a = g[tid] * rsqrtf(var + EPSF);
        CF[tid] = a;
        CF[64 + tid] = be[tid] - mean * a;
    }
    __syncthreads();
    int i = blockIdx.x * 256 + tid;
    half8 y = ((const half8*)Y)[i];
    int cb = (i & 7) * 8;
    float4 o0, o1;
    o0.x = fmaxf(CF[cb+0]*(float)y[0] + CF[64+cb+0], 0.f);
    o0.y = fmaxf(CF[cb+1]*(float)y[1] + CF[64+cb+1], 0.f);
    o0.z = fmaxf(CF[cb+2]*(float)y[2] + CF[64+cb+2], 0.f);
    o0.w = fmaxf(CF[cb+3]*(float)y[3] + CF[64+cb+3], 0.f);
    o1.x = fmaxf(CF[cb+4]*(float)y[4] + CF[64+cb+4], 0.f);
    o1.y = fmaxf(CF[cb+5]*(float)y[5] + CF[64+cb+5], 0.f);
    o1.z = fmaxf(CF[cb+6]*(float)y[6] + CF[64+cb+6], 0.f);
    o1.w = fmaxf(CF[cb+7]*(float)y[7] + CF[64+cb+7], 0.f);
    ((float4*)out)[2*i]   = o0;
    ((float4*)out)[2*i+1] = o1;
}

extern "C" void kernel_launch(void* const* d_in, const int* in_sizes, int n_in,
                              void* d_out, int out_size, void* d_ws, size_t ws_size,
                              hipStream_t stream) {
    const float* Q    = (const float*)d_in[0];
    const float* Kin  = (const float*)d_in[1];
    const float* mask = (const float*)d_in[2];
    const float* Wq = (const float*)d_in[4];
    const float* bq = (const float*)d_in[5];
    const float* gq = (const float*)d_in[6];
    const float* betaq = (const float*)d_in[7];
    const float* Wk = (const float*)d_in[8];
    const float* bk = (const float*)d_in[9];
    const float* gk = (const float*)d_in[10];
    const float* betak = (const float*)d_in[11];
    const float* Wv = (const float*)d_in[12];
    const float* bv = (const float*)d_in[13];
    const float* gv = (const float*)d_in[14];
    const float* betav = (const float*)d_in[15];
    const float* Wo = (const float*)d_in[16];
    const float* bo = (const float*)d_in[17];
    const float* go = (const float*)d_in[18];
    const float* betao = (const float*)d_in[19];

    const size_t TSZ = (size_t)RTOT * 64;
    _Float16* Yq = (_Float16*)d_ws;               // raw head-major
    _Float16* Yk = Yq + TSZ;
    _Float16* Vr = Yk + TSZ;                      // raw pre-interleaved, RTOT*72
    _Float16* Ob = Vr + (size_t)RTOT * 72;
    _Float16* Yo = Ob + TSZ;                      // [row][64] f16
    _Float16* zt = Yo + TSZ;                      // 8 * RTOT halfs
    float* stats = (float*)(zt + (size_t)8 * RTOT);  // 512 floats

    (void)hipMemsetAsync(stats, 0, 512 * sizeof(float), stream);

    dim3 gqkv(192, 3);
    gemm_qkv<<<gqkv, 512, 0, stream>>>(Q, Kin, mask, Wq, bq, Wk, bk, Wv, bv,
                                       Yq, Yk, Vr, zt, stats);

    attn_mfma<<<768, 512, 0, stream>>>(Yq, Yk, Vr, zt, stats,
                                       gq, betaq, gk, betak, gv, betav, Ob);

    gemm_o<<<192, 512, 0, stream>>>(Ob, Wo, bo, Yo, stats + 384);

    norm_relu16<<<1536, 256, 0, stream>>>(Yo, stats + 384, go, betao, (float*)d_out);
}